// Round 10
// baseline (409.044 us; speedup 1.0000x reference)
//
#include <hip/hip_runtime.h>

#define HID   256
#define BATCH 8
#define TT    256   // time steps (SEQ-1)
#define SEQL  257
#define VOCAB 29
#define EMB   64
#define TG    4     // attn t-tile
#define CH    8     // producer/consumer chunk (steps)
#define NCHK  (TT / CH)
#define HPAD  264   // padded LDS row (f16) to spread batch rows across banks

typedef _Float16 f16;
typedef f16  f16x8 __attribute__((ext_vector_type(8)));
typedef float f32x4 __attribute__((ext_vector_type(4)));

__device__ __forceinline__ float fast_tanh(float x) {
    float e = exp2f(x * 2.8853900817779268f);
    return 1.0f - 2.0f * __builtin_amdgcn_rcpf(1.0f + e);
}

// C0[t][b][i] = emb[x[b][t]] . W_ih0[i] + b_ih0[i] + b_hh0[i]; also zero the pipe flag.
__global__ __launch_bounds__(256) void pre0_kernel(
    const int* __restrict__ x, const float* __restrict__ embed,
    const float* __restrict__ Wih0, const float* __restrict__ bih0,
    const float* __restrict__ bhh0, float* __restrict__ C0, int* __restrict__ flag)
{
    if (blockIdx.x == 0 && threadIdx.x == 0) *flag = 0;
    int b  = blockIdx.x & 7;
    int t0 = (blockIdx.x >> 3) * 8;
    int tid = threadIdx.x;
    __shared__ float er[8][EMB];
    for (int idx = tid; idx < 8 * EMB; idx += 256) {
        int tt = idx >> 6, j = idx & 63;
        er[tt][j] = embed[x[b * SEQL + t0 + tt] * EMB + j];
    }
    __syncthreads();
    int i = tid;
    float base = bih0[i] + bhh0[i];
    float acc[8];
#pragma unroll
    for (int tt = 0; tt < 8; ++tt) acc[tt] = base;
    const float* wr = Wih0 + i * EMB;
    for (int j = 0; j < EMB; j += 4) {
        float4 w = *(const float4*)&wr[j];
#pragma unroll
        for (int tt = 0; tt < 8; ++tt) {
            float4 h = *(const float4*)&er[tt][j];
            acc[tt] += h.x * w.x + h.y * w.y + h.z * w.z + h.w * w.w;
        }
    }
#pragma unroll
    for (int tt = 0; tt < 8; ++tt)
        C0[((t0 + tt) * BATCH + b) * HID + i] = acc[tt];
}

// Fused 2-layer recurrence, M=8 (all batches in the A-fragment rows).
// grid=2: block 0 = layer 0 producer, block 1 = layer 1 consumer (chunk-pipelined
// via device-scope flag; WG0 never waits on WG1 -> deadlock-free).
__global__ __launch_bounds__(512) void recfused_kernel(
    const float* __restrict__ Whh0, const float* __restrict__ Wih1,
    const float* __restrict__ Whh1, const float* __restrict__ bih1,
    const float* __restrict__ bhh1, const float* __restrict__ C0,
    f16* __restrict__ H0h,          // [t][b][i] f16 (layer-0 output stream)
    float* __restrict__ Hs,         // [b][t][i] f32 (layer-1 output)
    int* __restrict__ flag)
{
    __shared__ __align__(16) f16 smem[(2 + CH) * 8 * HPAD];
    typedef f16 row_t[8][HPAD];
    row_t* buf = (row_t*)smem;                       // [2] state ping-pong
    row_t* stg = (row_t*)(smem + 2 * 8 * HPAD);      // [CH] staged h0 chunk (WG1)

    int tid = threadIdx.x;
    int wave = tid >> 6, lane = tid & 63;
    int lrow = lane & 15, lkg = lane >> 4;
    int bb = (lane >> 4) * 4;            // epilogue batch base (lanes < 32)
    int colA = wave * 32 + lrow;         // chunk-0 column for this lane
    const f32x4 Z = {0.f, 0.f, 0.f, 0.f};

    if (blockIdx.x == 0) {
        // ------------- layer 0 producer -------------
        for (int idx = tid; idx < 2 * 8 * HPAD; idx += 512) smem[idx] = (f16)0.f;
        // B-frag (verified layout): lane holds B[k=kt*32+lkg*8+e][n=wave*32+ct*16+lrow]
        f16x8 bf[8][2];
#pragma unroll
        for (int kt = 0; kt < 8; ++kt)
#pragma unroll
            for (int ct = 0; ct < 2; ++ct) {
                int n = wave * 32 + ct * 16 + lrow;
                const float* src = Whh0 + n * HID + kt * 32 + lkg * 8;
                f16x8 v;
#pragma unroll
                for (int e = 0; e < 8; ++e) v[e] = (f16)src[e];
                bf[kt][ct] = v;
            }
        __syncthreads();

        // persistent A-frags: rows 0-7 = batches; lanes with lrow>=8 stay zero
        f16x8 a[8];
#pragma unroll
        for (int kt = 0; kt < 8; ++kt)
#pragma unroll
            for (int e = 0; e < 8; ++e) a[kt][e] = (f16)0.f;

        const float* cp = C0;
        float c00=0,c01=0,c02=0,c03=0,c10=0,c11=0,c12=0,c13=0;
        int o0 = bb * HID + colA, o1 = o0 + 16;
        if (lane < 32) {
            c00=cp[o0]; c01=cp[o0+HID]; c02=cp[o0+2*HID]; c03=cp[o0+3*HID];
            c10=cp[o1]; c11=cp[o1+HID]; c12=cp[o1+2*HID]; c13=cp[o1+3*HID];
        }
        cp += BATCH * HID;
        f16* hp = H0h + bb * HID + colA;

#define WSTEP(CUR, NXT)                                                             \
    {                                                                               \
        float n00=0,n01=0,n02=0,n03=0,n10=0,n11=0,n12=0,n13=0;                      \
        if (lane < 32) {                                                            \
            n00=cp[o0]; n01=cp[o0+HID]; n02=cp[o0+2*HID]; n03=cp[o0+3*HID];         \
            n10=cp[o1]; n11=cp[o1+HID]; n12=cp[o1+2*HID]; n13=cp[o1+3*HID];         \
        }                                                                           \
        cp += BATCH * HID;                                                          \
        if (lrow < 8) {                                                             \
            _Pragma("unroll")                                                       \
            for (int kt = 0; kt < 8; ++kt)                                          \
                a[kt] = *(const f16x8*)&buf[CUR][lrow][kt * 32 + lkg * 8];          \
        }                                                                           \
        f32x4 p00 = __builtin_amdgcn_mfma_f32_16x16x32_f16(a[0], bf[0][0], Z, 0, 0, 0); \
        f32x4 p01 = __builtin_amdgcn_mfma_f32_16x16x32_f16(a[0], bf[0][1], Z, 0, 0, 0); \
        f32x4 p10 = __builtin_amdgcn_mfma_f32_16x16x32_f16(a[2], bf[2][0], Z, 0, 0, 0); \
        f32x4 p11 = __builtin_amdgcn_mfma_f32_16x16x32_f16(a[2], bf[2][1], Z, 0, 0, 0); \
        f32x4 p20 = __builtin_amdgcn_mfma_f32_16x16x32_f16(a[4], bf[4][0], Z, 0, 0, 0); \
        f32x4 p21 = __builtin_amdgcn_mfma_f32_16x16x32_f16(a[4], bf[4][1], Z, 0, 0, 0); \
        f32x4 p30 = __builtin_amdgcn_mfma_f32_16x16x32_f16(a[6], bf[6][0], Z, 0, 0, 0); \
        f32x4 p31 = __builtin_amdgcn_mfma_f32_16x16x32_f16(a[6], bf[6][1], Z, 0, 0, 0); \
        p00 = __builtin_amdgcn_mfma_f32_16x16x32_f16(a[1], bf[1][0], p00, 0, 0, 0); \
        p01 = __builtin_amdgcn_mfma_f32_16x16x32_f16(a[1], bf[1][1], p01, 0, 0, 0); \
        p10 = __builtin_amdgcn_mfma_f32_16x16x32_f16(a[3], bf[3][0], p10, 0, 0, 0); \
        p11 = __builtin_amdgcn_mfma_f32_16x16x32_f16(a[3], bf[3][1], p11, 0, 0, 0); \
        p20 = __builtin_amdgcn_mfma_f32_16x16x32_f16(a[5], bf[5][0], p20, 0, 0, 0); \
        p21 = __builtin_amdgcn_mfma_f32_16x16x32_f16(a[5], bf[5][1], p21, 0, 0, 0); \
        p30 = __builtin_amdgcn_mfma_f32_16x16x32_f16(a[7], bf[7][0], p30, 0, 0, 0); \
        p31 = __builtin_amdgcn_mfma_f32_16x16x32_f16(a[7], bf[7][1], p31, 0, 0, 0); \
        if (lane < 32) {                                                            \
            float w00 = fast_tanh(((p00[0]+p10[0])+(p20[0]+p30[0])) + c00);         \
            float w01 = fast_tanh(((p00[1]+p10[1])+(p20[1]+p30[1])) + c01);         \
            float w02 = fast_tanh(((p00[2]+p10[2])+(p20[2]+p30[2])) + c02);         \
            float w03 = fast_tanh(((p00[3]+p10[3])+(p20[3]+p30[3])) + c03);         \
            float w10 = fast_tanh(((p01[0]+p11[0])+(p21[0]+p31[0])) + c10);         \
            float w11 = fast_tanh(((p01[1]+p11[1])+(p21[1]+p31[1])) + c11);         \
            float w12 = fast_tanh(((p01[2]+p11[2])+(p21[2]+p31[2])) + c12);         \
            float w13 = fast_tanh(((p01[3]+p11[3])+(p21[3]+p31[3])) + c13);         \
            buf[NXT][bb+0][colA] = (f16)w00; buf[NXT][bb+1][colA] = (f16)w01;       \
            buf[NXT][bb+2][colA] = (f16)w02; buf[NXT][bb+3][colA] = (f16)w03;       \
            buf[NXT][bb+0][colA+16] = (f16)w10; buf[NXT][bb+1][colA+16] = (f16)w11; \
            buf[NXT][bb+2][colA+16] = (f16)w12; buf[NXT][bb+3][colA+16] = (f16)w13; \
            hp[0]       = (f16)w00; hp[HID]      = (f16)w01;                        \
            hp[2*HID]   = (f16)w02; hp[3*HID]    = (f16)w03;                        \
            hp[16]      = (f16)w10; hp[HID+16]   = (f16)w11;                        \
            hp[2*HID+16]= (f16)w12; hp[3*HID+16] = (f16)w13;                        \
        }                                                                           \
        hp += BATCH * HID;                                                          \
        c00=n00; c01=n01; c02=n02; c03=n03; c10=n10; c11=n11; c12=n12; c13=n13;     \
        asm volatile("s_waitcnt lgkmcnt(0)\n\ts_barrier" ::: "memory");             \
    }

        for (int ch = 0; ch < NCHK; ++ch) {
            WSTEP(0, 1) WSTEP(1, 0) WSTEP(0, 1) WSTEP(1, 0)
            WSTEP(0, 1) WSTEP(1, 0) WSTEP(0, 1) WSTEP(1, 0)
            __syncthreads();   // drain all global h0 stores (vmcnt 0 in barrier)
            if (tid == 0) {
                __threadfence();
                __hip_atomic_store(flag, ch + 1, __ATOMIC_RELEASE, __HIP_MEMORY_SCOPE_AGENT);
            }
        }
#undef WSTEP
    } else {
        // ------------- layer 1 consumer -------------
        for (int idx = tid; idx < 2 * 8 * HPAD; idx += 512) smem[idx] = (f16)0.f;
        f16x8 bfI[8][2], bfH[8][2];
#pragma unroll
        for (int kt = 0; kt < 8; ++kt)
#pragma unroll
            for (int ct = 0; ct < 2; ++ct) {
                int n = wave * 32 + ct * 16 + lrow;
                const float* sI = Wih1 + n * HID + kt * 32 + lkg * 8;
                const float* sH = Whh1 + n * HID + kt * 32 + lkg * 8;
                f16x8 vI, vH;
#pragma unroll
                for (int e = 0; e < 8; ++e) { vI[e] = (f16)sI[e]; vH[e] = (f16)sH[e]; }
                bfI[kt][ct] = vI; bfH[kt][ct] = vH;
            }
        float bs0 = 0.f, bs1 = 0.f;
        if (lane < 32) {
            bs0 = bih1[colA] + bhh1[colA];
            bs1 = bih1[colA + 16] + bhh1[colA + 16];
        }
        __syncthreads();

        f16x8 ai[8], ah[8];
#pragma unroll
        for (int kt = 0; kt < 8; ++kt)
#pragma unroll
            for (int e = 0; e < 8; ++e) { ai[kt][e] = (f16)0.f; ah[kt][e] = (f16)0.f; }

        float* hq = Hs + (size_t)bb * TT * HID + colA;

#define VSTEP(CUR, NXT, LT)                                                         \
    {                                                                               \
        if (lrow < 8) {                                                             \
            _Pragma("unroll")                                                       \
            for (int kt = 0; kt < 8; ++kt) {                                        \
                ai[kt] = *(const f16x8*)&stg[LT][lrow][kt * 32 + lkg * 8];          \
                ah[kt] = *(const f16x8*)&buf[CUR][lrow][kt * 32 + lkg * 8];         \
            }                                                                       \
        }                                                                           \
        f32x4 qI0 = __builtin_amdgcn_mfma_f32_16x16x32_f16(ai[0], bfI[0][0], Z, 0, 0, 0); \
        f32x4 qI1 = __builtin_amdgcn_mfma_f32_16x16x32_f16(ai[0], bfI[0][1], Z, 0, 0, 0); \
        f32x4 qH0 = __builtin_amdgcn_mfma_f32_16x16x32_f16(ah[0], bfH[0][0], Z, 0, 0, 0); \
        f32x4 qH1 = __builtin_amdgcn_mfma_f32_16x16x32_f16(ah[0], bfH[0][1], Z, 0, 0, 0); \
        _Pragma("unroll")                                                           \
        for (int kt = 1; kt < 8; ++kt) {                                            \
            qI0 = __builtin_amdgcn_mfma_f32_16x16x32_f16(ai[kt], bfI[kt][0], qI0, 0, 0, 0); \
            qI1 = __builtin_amdgcn_mfma_f32_16x16x32_f16(ai[kt], bfI[kt][1], qI1, 0, 0, 0); \
            qH0 = __builtin_amdgcn_mfma_f32_16x16x32_f16(ah[kt], bfH[kt][0], qH0, 0, 0, 0); \
            qH1 = __builtin_amdgcn_mfma_f32_16x16x32_f16(ah[kt], bfH[kt][1], qH1, 0, 0, 0); \
        }                                                                           \
        if (lane < 32) {                                                            \
            float w00 = fast_tanh(qI0[0] + qH0[0] + bs0);                           \
            float w01 = fast_tanh(qI0[1] + qH0[1] + bs0);                           \
            float w02 = fast_tanh(qI0[2] + qH0[2] + bs0);                           \
            float w03 = fast_tanh(qI0[3] + qH0[3] + bs0);                           \
            float w10 = fast_tanh(qI1[0] + qH1[0] + bs1);                           \
            float w11 = fast_tanh(qI1[1] + qH1[1] + bs1);                           \
            float w12 = fast_tanh(qI1[2] + qH1[2] + bs1);                           \
            float w13 = fast_tanh(qI1[3] + qH1[3] + bs1);                           \
            buf[NXT][bb+0][colA] = (f16)w00; buf[NXT][bb+1][colA] = (f16)w01;       \
            buf[NXT][bb+2][colA] = (f16)w02; buf[NXT][bb+3][colA] = (f16)w03;       \
            buf[NXT][bb+0][colA+16] = (f16)w10; buf[NXT][bb+1][colA+16] = (f16)w11; \
            buf[NXT][bb+2][colA+16] = (f16)w12; buf[NXT][bb+3][colA+16] = (f16)w13; \
            hq[0]                 = w00; hq[(size_t)TT*HID]     = w01;              \
            hq[(size_t)2*TT*HID]  = w02; hq[(size_t)3*TT*HID]   = w03;              \
            hq[16]                = w10; hq[(size_t)TT*HID+16]  = w11;              \
            hq[(size_t)2*TT*HID+16] = w12; hq[(size_t)3*TT*HID+16] = w13;           \
        }                                                                           \
        hq += HID;                                                                  \
        asm volatile("s_waitcnt lgkmcnt(0)\n\ts_barrier" ::: "memory");             \
    }

        for (int ch = 0; ch < NCHK; ++ch) {
            if (tid == 0) {
                while (__hip_atomic_load(flag, __ATOMIC_ACQUIRE, __HIP_MEMORY_SCOPE_AGENT) < ch + 1)
                    __builtin_amdgcn_s_sleep(2);
            }
            __syncthreads();
            // stage this chunk's h0 (f16, contiguous [t][b][i])
            const f16* src = H0h + (size_t)ch * CH * BATCH * HID;
#pragma unroll
            for (int e = 0; e < 4; ++e) {
                int v = tid + e * 512;          // 2048 vectors of 8 f16
                int lt = v >> 8;
                int b8 = (v & 255) >> 5;
                int ii = (v & 31) * 8;
                *(f16x8*)&stg[lt][b8][ii] = *(const f16x8*)(src + (size_t)v * 8);
            }
            __syncthreads();
            VSTEP(0, 1, 0) VSTEP(1, 0, 1) VSTEP(0, 1, 2) VSTEP(1, 0, 3)
            VSTEP(0, 1, 4) VSTEP(1, 0, 5) VSTEP(0, 1, 6) VSTEP(1, 0, 7)
        }
#undef VSTEP
    }
}

// tq[b][t][i] = tanh(Hs@Wq^T), tkT[b][i][t] = tanh(Hs@Wk^T)
__global__ __launch_bounds__(256) void gemmqk_kernel(
    const float* __restrict__ In, const float* __restrict__ Wq,
    const float* __restrict__ Wk, float* __restrict__ Oq, float* __restrict__ OkT)
{
    int b  = blockIdx.x & 7;
    int t0 = (blockIdx.x >> 3) * 8;
    int tid = threadIdx.x;
    __shared__ float hs[8][HID];
    for (int idx = tid; idx < 8 * HID; idx += 256) {
        int tt = idx >> 8, j = idx & 255;
        hs[tt][j] = In[((size_t)b * TT + t0 + tt) * HID + j];
    }
    __syncthreads();
    int i = tid;
    float aq[8], ak[8];
#pragma unroll
    for (int tt = 0; tt < 8; ++tt) { aq[tt] = 0.f; ak[tt] = 0.f; }
    const float* wq = Wq + i * HID;
    const float* wk = Wk + i * HID;
    for (int j = 0; j < HID; j += 4) {
        float4 q = *(const float4*)&wq[j];
        float4 k = *(const float4*)&wk[j];
#pragma unroll
        for (int tt = 0; tt < 8; ++tt) {
            float4 h = *(const float4*)&hs[tt][j];
            aq[tt] += h.x * q.x + h.y * q.y + h.z * q.z + h.w * q.w;
            ak[tt] += h.x * k.x + h.y * k.y + h.z * k.z + h.w * k.w;
        }
    }
#pragma unroll
    for (int tt = 0; tt < 8; ++tt)
        Oq[((size_t)b * TT + t0 + tt) * HID + i] = fast_tanh(aq[tt]);
    float4 kv0 = { fast_tanh(ak[0]), fast_tanh(ak[1]), fast_tanh(ak[2]), fast_tanh(ak[3]) };
    float4 kv1 = { fast_tanh(ak[4]), fast_tanh(ak[5]), fast_tanh(ak[6]), fast_tanh(ak[7]) };
    float* ko = OkT + ((size_t)b * HID + i) * TT + t0;
    *(float4*)&ko[0] = kv0;
    *(float4*)&ko[4] = kv1;
}

// attn (R8-verified): tanh addition identity; batch pinned to XCD; padded cvec.
__global__ __launch_bounds__(256) void attn_kernel(
    const float* __restrict__ tq, const float* __restrict__ tkT,
    const float* __restrict__ vvec, const float* __restrict__ Hs,
    const float* __restrict__ Wfc, const float* __restrict__ bfc,
    float* __restrict__ out)
{
    int b  = blockIdx.x & 7;
    int t0 = (blockIdx.x >> 3) * TG;
    int tid = threadIdx.x;
    int wave = tid >> 6, lane = tid & 63;
    __shared__ float qs[TG][HID], vs[HID], alpha[TG][HID];
    __shared__ float cvec[TG][8][68];
    __shared__ float redm[4][TG], reds[4][TG];
#pragma unroll
    for (int j = 0; j < TG; ++j)
        qs[j][tid] = tq[((size_t)b * TT + t0 + j) * HID + tid];
    vs[tid] = vvec[tid];
    __syncthreads();

    float sc[TG];
#pragma unroll
    for (int j = 0; j < TG; ++j) sc[j] = -1e30f;
    if ((wave << 6) < t0 + TG) {
        const float* kT = tkT + (size_t)b * HID * TT + tid;
        float a0 = 0.f, a1 = 0.f, a2 = 0.f, a3 = 0.f;
        for (int jj = 0; jj < HID; jj += 4) {
            float k0 = kT[(size_t)(jj + 0) * TT];
            float k1 = kT[(size_t)(jj + 1) * TT];
            float k2 = kT[(size_t)(jj + 2) * TT];
            float k3 = kT[(size_t)(jj + 3) * TT];
            float4 vv = *(const float4*)&vs[jj];
            float4 q0 = *(const float4*)&qs[0][jj];
            float4 q1 = *(const float4*)&qs[1][jj];
            float4 q2 = *(const float4*)&qs[2][jj];
            float4 q3 = *(const float4*)&qs[3][jj];
#define TADD(qc, kc, vc, acc) { float num = qc + kc; float den = __builtin_fmaf(qc, kc, 1.f); acc += vc * num * __builtin_amdgcn_rcpf(den); }
            TADD(q0.x, k0, vv.x, a0) TADD(q0.y, k1, vv.y, a0) TADD(q0.z, k2, vv.z, a0) TADD(q0.w, k3, vv.w, a0)
            TADD(q1.x, k0, vv.x, a1) TADD(q1.y, k1, vv.y, a1) TADD(q1.z, k2, vv.z, a1) TADD(q1.w, k3, vv.w, a1)
            TADD(q2.x, k0, vv.x, a2) TADD(q2.y, k1, vv.y, a2) TADD(q2.z, k2, vv.z, a2) TADD(q2.w, k3, vv.w, a2)
            TADD(q3.x, k0, vv.x, a3) TADD(q3.y, k1, vv.y, a3) TADD(q3.z, k2, vv.z, a3) TADD(q3.w, k3, vv.w, a3)
#undef TADD
        }
        if (tid < t0 + 0) sc[0] = a0;
        if (tid < t0 + 1) sc[1] = a1;
        if (tid < t0 + 2) sc[2] = a2;
        if (tid < t0 + 3) sc[3] = a3;
    }
    float m0 = sc[0], m1 = sc[1], m2 = sc[2], m3 = sc[3];
#pragma unroll
    for (int off = 32; off; off >>= 1) {
        m0 = fmaxf(m0, __shfl_down(m0, off));
        m1 = fmaxf(m1, __shfl_down(m1, off));
        m2 = fmaxf(m2, __shfl_down(m2, off));
        m3 = fmaxf(m3, __shfl_down(m3, off));
    }
    if (lane == 0) { redm[wave][0] = m0; redm[wave][1] = m1; redm[wave][2] = m2; redm[wave][3] = m3; }
    __syncthreads();
    float ej[TG];
#pragma unroll
    for (int j = 0; j < TG; ++j) {
        float m = fmaxf(fmaxf(redm[0][j], redm[1][j]), fmaxf(redm[2][j], redm[3][j]));
        ej[j] = (tid < t0 + j) ? exp2f((sc[j] - m) * 1.4426950408889634f) : 0.f;
    }
    float z0 = ej[0], z1 = ej[1], z2 = ej[2], z3 = ej[3];
#pragma unroll
    for (int off = 32; off; off >>= 1) {
        z0 += __shfl_down(z0, off);
        z1 += __shfl_down(z1, off);
        z2 += __shfl_down(z2, off);
        z3 += __shfl_down(z3, off);
    }
    if (lane == 0) { reds[wave][0] = z0; reds[wave][1] = z1; reds[wave][2] = z2; reds[wave][3] = z3; }
    __syncthreads();
#pragma unroll
    for (int j = 0; j < TG; ++j) {
        float z = reds[0][j] + reds[1][j] + reds[2][j] + reds[3][j];
        alpha[j][tid] = (t0 + j == 0) ? 0.f : ej[j] * __builtin_amdgcn_rcpf(z);
    }
    __syncthreads();

    float c0 = 0.f, c1 = 0.f, c2 = 0.f, c3 = 0.f;
    const float* hb = Hs + (size_t)b * TT * HID;
    for (int s = 0; s < t0 + TG; s += 4) {
        float4 av0 = *(const float4*)&alpha[0][s];
        float4 av1 = *(const float4*)&alpha[1][s];
        float4 av2 = *(const float4*)&alpha[2][s];
        float4 av3 = *(const float4*)&alpha[3][s];
        float h0 = hb[(s + 0) * HID + tid];
        float h1 = hb[(s + 1) * HID + tid];
        float h2 = hb[(s + 2) * HID + tid];
        float h3 = hb[(s + 3) * HID + tid];
        c0 += av0.x * h0 + av0.y * h1 + av0.z * h2 + av0.w * h3;
        c1 += av1.x * h0 + av1.y * h1 + av1.z * h2 + av1.w * h3;
        c2 += av2.x * h0 + av2.y * h1 + av2.z * h2 + av2.w * h3;
        c3 += av3.x * h0 + av3.y * h1 + av3.z * h2 + av3.w * h3;
    }
    {
        int ph = tid >> 6, jj = tid & 63;
        cvec[0][ph][jj] = hb[(size_t)(t0 + 0) * HID + tid]; cvec[0][4 + ph][jj] = c0;
        cvec[1][ph][jj] = hb[(size_t)(t0 + 1) * HID + tid]; cvec[1][4 + ph][jj] = c1;
        cvec[2][ph][jj] = hb[(size_t)(t0 + 2) * HID + tid]; cvec[2][4 + ph][jj] = c2;
        cvec[3][ph][jj] = hb[(size_t)(t0 + 3) * HID + tid]; cvec[3][4 + ph][jj] = c3;
    }
    __syncthreads();

    if (tid < VOCAB * 8) {
        int o = tid >> 3, p = tid & 7;
        const float* wr = Wfc + o * 2 * HID + p * 64;
#pragma unroll
        for (int j = 0; j < TG; ++j) {
            const float* cv = &cvec[j][p][0];
            float a = 0.f;
            for (int jj = 0; jj < 64; jj += 4) {
                float4 w  = *(const float4*)&wr[jj];
                float4 cc = *(const float4*)&cv[jj];
                a += w.x * cc.x + w.y * cc.y + w.z * cc.z + w.w * cc.w;
            }
            a += __shfl_down(a, 4);
            a += __shfl_down(a, 2);
            a += __shfl_down(a, 1);
            if (p == 0) out[((size_t)b * TT + t0 + j) * VOCAB + o] = a + bfc[o];
        }
    }
}

extern "C" void kernel_launch(void* const* d_in, const int* in_sizes, int n_in,
                              void* d_out, int out_size, void* d_ws, size_t ws_size,
                              hipStream_t stream)
{
    (void)in_sizes; (void)n_in; (void)out_size; (void)ws_size;
    const int*   x     = (const int*)d_in[0];
    const float* embed = (const float*)d_in[1];
    const float* Wih0  = (const float*)d_in[2];
    const float* bih0  = (const float*)d_in[3];
    const float* Whh0  = (const float*)d_in[4];
    const float* bhh0  = (const float*)d_in[5];
    const float* Wih1  = (const float*)d_in[6];
    const float* bih1  = (const float*)d_in[7];
    const float* Whh1  = (const float*)d_in[8];
    const float* bhh1  = (const float*)d_in[9];
    const float* Wq    = (const float*)d_in[10];
    const float* Wk    = (const float*)d_in[11];
    const float* vvec  = (const float*)d_in[12];
    const float* Wfc   = (const float*)d_in[13];
    const float* bfc   = (const float*)d_in[14];
    float* out = (float*)d_out;
    float* ws  = (float*)d_ws;

    const size_t SZ = (size_t)TT * BATCH * HID;  // 524288 floats = 2 MB
    float* C0  = ws;                 // live during recfused
    float* Hs  = ws + SZ;            // live during recfused..attn
    float* tqb = ws + 2 * SZ;        // gemmqk output (after recfused)
    float* tkT = ws + 3 * SZ;        // gemmqk output (after recfused)
    f16*   H0h = (f16*)(ws + 2 * SZ);   // f16 h0 stream, dead before tqb written
    int*   flag = (int*)(ws + 3 * SZ);  // dead before tkT written

    pre0_kernel<<<256, 256, 0, stream>>>(x, embed, Wih0, bih0, bhh0, C0, flag);
    recfused_kernel<<<2, 512, 0, stream>>>(Whh0, Wih1, Whh1, bih1, bhh1, C0, H0h, Hs, flag);
    gemmqk_kernel<<<256, 256, 0, stream>>>(Hs, Wq, Wk, tqb, tkT);
    attn_kernel<<<512, 256, 0, stream>>>(tqb, tkT, vvec, Hs, Wfc, bfc, out);
}

// Round 11
// 240.088 us; speedup vs baseline: 1.7037x; 1.7037x over previous
//
#include <hip/hip_runtime.h>

#define HID   256
#define BATCH 8
#define TT    256   // time steps (SEQ-1)
#define SEQL  257
#define VOCAB 29
#define EMB   64
#define TG    4     // attn t-tile
#define CH    8     // pipeline chunk (steps)
#define NCHK  (TT / CH)

typedef _Float16 f16;
typedef f16  f16x8 __attribute__((ext_vector_type(8)));
typedef float f32x4 __attribute__((ext_vector_type(4)));

__device__ __forceinline__ float fast_tanh(float x) {
    float e = exp2f(x * 2.8853900817779268f);
    return 1.0f - 2.0f * __builtin_amdgcn_rcpf(1.0f + e);
}

// C0[t][b][i] = emb[x[b][t]] . W_ih0[i] + b_ih0[i] + b_hh0[i]; zero the 16 pipe flags.
__global__ __launch_bounds__(256) void pre0_kernel(
    const int* __restrict__ x, const float* __restrict__ embed,
    const float* __restrict__ Wih0, const float* __restrict__ bih0,
    const float* __restrict__ bhh0, float* __restrict__ C0, int* __restrict__ flags)
{
    if (blockIdx.x == 0 && threadIdx.x < 16) flags[threadIdx.x] = 0;
    int b  = blockIdx.x & 7;
    int t0 = (blockIdx.x >> 3) * 8;
    int tid = threadIdx.x;
    __shared__ float er[8][EMB];
    for (int idx = tid; idx < 8 * EMB; idx += 256) {
        int tt = idx >> 6, j = idx & 63;
        er[tt][j] = embed[x[b * SEQL + t0 + tt] * EMB + j];
    }
    __syncthreads();
    int i = tid;
    float base = bih0[i] + bhh0[i];
    float acc[8];
#pragma unroll
    for (int tt = 0; tt < 8; ++tt) acc[tt] = base;
    const float* wr = Wih0 + i * EMB;
    for (int j = 0; j < EMB; j += 4) {
        float4 w = *(const float4*)&wr[j];
#pragma unroll
        for (int tt = 0; tt < 8; ++tt) {
            float4 h = *(const float4*)&er[tt][j];
            acc[tt] += h.x * w.x + h.y * w.y + h.z * w.z + h.w * w.w;
        }
    }
#pragma unroll
    for (int tt = 0; tt < 8; ++tt)
        C0[((t0 + tt) * BATCH + b) * HID + i] = acc[tt];
}

// 3-stage chunk pipeline, every WG holds ONE weight matrix (64 VGPR):
//  blocks 0-7  (A): layer0 rec per batch (Whh0), h0 -> f16 global; flagA per chunk
//  blocks 8-15 (B): C1 = Wih1 . h0chunk + biases, M=8 over chunk timesteps; flagB
//  blocks 16-23(C): layer1 rec per batch (Whh1), reads C1 chunk-gated, writes Hs
__global__ __launch_bounds__(512) void rec3_kernel(
    const float* __restrict__ Whh0, const float* __restrict__ Wih1,
    const float* __restrict__ Whh1, const float* __restrict__ bih1,
    const float* __restrict__ bhh1, const float* __restrict__ C0,
    f16* __restrict__ H0h, float* __restrict__ C1,
    float* __restrict__ Hs, int* __restrict__ flags)
{
    __shared__ f16 hbuf[2][HID];
    __shared__ __align__(16) f16 stg[CH][HID];
    int tid = threadIdx.x;
    int wave = tid >> 6, lane = tid & 63;
    int lrow = lane & 15, lkg = lane >> 4;
    int role = blockIdx.x >> 3;
    int b = blockIdx.x & 7;
    int i0 = wave * 32 + lrow, i1 = i0 + 16;
    const f32x4 Z = {0.f, 0.f, 0.f, 0.f};

    // persistent A-fragments: zero once; masked ds_reads only touch real rows
    f16x8 a[8];
#pragma unroll
    for (int kt = 0; kt < 8; ++kt)
#pragma unroll
        for (int e = 0; e < 8; ++e) a[kt][e] = (f16)0.f;

    if (role == 0) {
        // ---------------- A: layer 0 (R8-proven form) ----------------
        for (int idx = tid; idx < 2 * HID; idx += 512) ((f16*)hbuf)[idx] = (f16)0.f;
        f16x8 bf[8][2];
#pragma unroll
        for (int kt = 0; kt < 8; ++kt)
#pragma unroll
            for (int ct = 0; ct < 2; ++ct) {
                int n = wave * 32 + ct * 16 + lrow;
                const float* src = Whh0 + n * HID + kt * 32 + lkg * 8;
                f16x8 v;
#pragma unroll
                for (int e = 0; e < 8; ++e) v[e] = (f16)src[e];
                bf[kt][ct] = v;
            }
        __syncthreads();

        const float* cp = C0 + b * HID;
        float c0 = cp[i0], c1 = cp[i1];
        cp += BATCH * HID;
        f16* hp = H0h + (size_t)b * TT * HID;

#define ASTEP(CUR, NXT)                                                             \
    {                                                                               \
        float cn0 = cp[i0];                                                         \
        float cn1 = cp[i1];                                                         \
        cp += BATCH * HID;                                                          \
        if (lrow == 0) {                                                            \
            _Pragma("unroll")                                                       \
            for (int kt = 0; kt < 8; ++kt)                                          \
                a[kt] = *(const f16x8*)&hbuf[CUR][kt * 32 + lkg * 8];               \
        }                                                                           \
        f32x4 p00 = __builtin_amdgcn_mfma_f32_16x16x32_f16(a[0], bf[0][0], Z, 0, 0, 0); \
        f32x4 p01 = __builtin_amdgcn_mfma_f32_16x16x32_f16(a[0], bf[0][1], Z, 0, 0, 0); \
        f32x4 p10 = __builtin_amdgcn_mfma_f32_16x16x32_f16(a[2], bf[2][0], Z, 0, 0, 0); \
        f32x4 p11 = __builtin_amdgcn_mfma_f32_16x16x32_f16(a[2], bf[2][1], Z, 0, 0, 0); \
        f32x4 p20 = __builtin_amdgcn_mfma_f32_16x16x32_f16(a[4], bf[4][0], Z, 0, 0, 0); \
        f32x4 p21 = __builtin_amdgcn_mfma_f32_16x16x32_f16(a[4], bf[4][1], Z, 0, 0, 0); \
        f32x4 p30 = __builtin_amdgcn_mfma_f32_16x16x32_f16(a[6], bf[6][0], Z, 0, 0, 0); \
        f32x4 p31 = __builtin_amdgcn_mfma_f32_16x16x32_f16(a[6], bf[6][1], Z, 0, 0, 0); \
        p00 = __builtin_amdgcn_mfma_f32_16x16x32_f16(a[1], bf[1][0], p00, 0, 0, 0); \
        p01 = __builtin_amdgcn_mfma_f32_16x16x32_f16(a[1], bf[1][1], p01, 0, 0, 0); \
        p10 = __builtin_amdgcn_mfma_f32_16x16x32_f16(a[3], bf[3][0], p10, 0, 0, 0); \
        p11 = __builtin_amdgcn_mfma_f32_16x16x32_f16(a[3], bf[3][1], p11, 0, 0, 0); \
        p20 = __builtin_amdgcn_mfma_f32_16x16x32_f16(a[5], bf[5][0], p20, 0, 0, 0); \
        p21 = __builtin_amdgcn_mfma_f32_16x16x32_f16(a[5], bf[5][1], p21, 0, 0, 0); \
        p30 = __builtin_amdgcn_mfma_f32_16x16x32_f16(a[7], bf[7][0], p30, 0, 0, 0); \
        p31 = __builtin_amdgcn_mfma_f32_16x16x32_f16(a[7], bf[7][1], p31, 0, 0, 0); \
        float v0 = fast_tanh(((p00[0] + p10[0]) + (p20[0] + p30[0])) + c0);         \
        float v1 = fast_tanh(((p01[0] + p11[0]) + (p21[0] + p31[0])) + c1);         \
        f16 hv0 = (f16)v0, hv1 = (f16)v1;                                           \
        if (lane < 16) {                                                            \
            hbuf[NXT][i0] = hv0;                                                    \
            hbuf[NXT][i1] = hv1;                                                    \
            hp[i0] = hv0;                                                           \
            hp[i1] = hv1;                                                           \
        }                                                                           \
        hp += HID;                                                                  \
        c0 = cn0; c1 = cn1;                                                         \
        asm volatile("s_waitcnt lgkmcnt(0)\n\ts_barrier" ::: "memory");             \
    }

        for (int ch = 0; ch < NCHK; ++ch) {
            ASTEP(0, 1) ASTEP(1, 0) ASTEP(0, 1) ASTEP(1, 0)
            ASTEP(0, 1) ASTEP(1, 0) ASTEP(0, 1) ASTEP(1, 0)
            __syncthreads();   // drain all h0 stores
            if (tid == 0) {
                __threadfence();
                __hip_atomic_store(&flags[b], ch + 1, __ATOMIC_RELEASE, __HIP_MEMORY_SCOPE_AGENT);
            }
        }
#undef ASTEP
    } else if (role == 1) {
        // ---------------- B: C1 chunk producer (M=8 over timesteps) ----------------
        f16x8 bfI[8][2];
#pragma unroll
        for (int kt = 0; kt < 8; ++kt)
#pragma unroll
            for (int ct = 0; ct < 2; ++ct) {
                int n = wave * 32 + ct * 16 + lrow;
                const float* src = Wih1 + n * HID + kt * 32 + lkg * 8;
                f16x8 v;
#pragma unroll
                for (int e = 0; e < 8; ++e) v[e] = (f16)src[e];
                bfI[kt][ct] = v;
            }
        int col0 = wave * 32 + (lane & 15), col1 = col0 + 16;
        float bv0 = bih1[col0] + bhh1[col0];
        float bv1 = bih1[col1] + bhh1[col1];
        const f16* hsrc = H0h + (size_t)b * TT * HID;
        float* cbase = C1 + (size_t)b * TT * HID;

        for (int ch = 0; ch < NCHK; ++ch) {
            if (tid == 0) {
                while (__hip_atomic_load(&flags[b], __ATOMIC_ACQUIRE, __HIP_MEMORY_SCOPE_AGENT) < ch + 1)
                    __builtin_amdgcn_s_sleep(2);
            }
            __syncthreads();
            // stage 8x256 f16 chunk (4 KB)
            if (tid < 256)
                *(f16x8*)((f16*)stg + tid * 8) =
                    *(const f16x8*)(hsrc + (size_t)ch * CH * HID + tid * 8);
            __syncthreads();
            if (lrow < 8) {
#pragma unroll
                for (int kt = 0; kt < 8; ++kt)
                    a[kt] = *(const f16x8*)&stg[lrow][kt * 32 + lkg * 8];
            }
            f32x4 u0 = __builtin_amdgcn_mfma_f32_16x16x32_f16(a[0], bfI[0][0], Z, 0, 0, 0);
            f32x4 u1 = __builtin_amdgcn_mfma_f32_16x16x32_f16(a[0], bfI[0][1], Z, 0, 0, 0);
#pragma unroll
            for (int kt = 1; kt < 8; ++kt) {
                u0 = __builtin_amdgcn_mfma_f32_16x16x32_f16(a[kt], bfI[kt][0], u0, 0, 0, 0);
                u1 = __builtin_amdgcn_mfma_f32_16x16x32_f16(a[kt], bfI[kt][1], u1, 0, 0, 0);
            }
            if (lane < 32) {   // D rows 0-7 = chunk timesteps
                float* co = cbase + (size_t)(ch * CH + (lane >> 4) * 4) * HID;
                co[0 * HID + col0] = u0[0] + bv0;
                co[1 * HID + col0] = u0[1] + bv0;
                co[2 * HID + col0] = u0[2] + bv0;
                co[3 * HID + col0] = u0[3] + bv0;
                co[0 * HID + col1] = u1[0] + bv1;
                co[1 * HID + col1] = u1[1] + bv1;
                co[2 * HID + col1] = u1[2] + bv1;
                co[3 * HID + col1] = u1[3] + bv1;
            }
            __syncthreads();   // drain C1 stores
            if (tid == 0) {
                __threadfence();
                __hip_atomic_store(&flags[8 + b], ch + 1, __ATOMIC_RELEASE, __HIP_MEMORY_SCOPE_AGENT);
            }
        }
    } else {
        // ---------------- C: layer 1 (R8-proven form, chunk-gated) ----------------
        for (int idx = tid; idx < 2 * HID; idx += 512) ((f16*)hbuf)[idx] = (f16)0.f;
        f16x8 bf[8][2];
#pragma unroll
        for (int kt = 0; kt < 8; ++kt)
#pragma unroll
            for (int ct = 0; ct < 2; ++ct) {
                int n = wave * 32 + ct * 16 + lrow;
                const float* src = Whh1 + n * HID + kt * 32 + lkg * 8;
                f16x8 v;
#pragma unroll
                for (int e = 0; e < 8; ++e) v[e] = (f16)src[e];
                bf[kt][ct] = v;
            }
        __syncthreads();
        float* ho = Hs + (size_t)b * TT * HID;
        const float* cq = C1 + (size_t)b * TT * HID;

#define CSTEP(CUR, NXT, CV0, CV1)                                                   \
    {                                                                               \
        if (lrow == 0) {                                                            \
            _Pragma("unroll")                                                       \
            for (int kt = 0; kt < 8; ++kt)                                          \
                a[kt] = *(const f16x8*)&hbuf[CUR][kt * 32 + lkg * 8];               \
        }                                                                           \
        f32x4 p00 = __builtin_amdgcn_mfma_f32_16x16x32_f16(a[0], bf[0][0], Z, 0, 0, 0); \
        f32x4 p01 = __builtin_amdgcn_mfma_f32_16x16x32_f16(a[0], bf[0][1], Z, 0, 0, 0); \
        f32x4 p10 = __builtin_amdgcn_mfma_f32_16x16x32_f16(a[2], bf[2][0], Z, 0, 0, 0); \
        f32x4 p11 = __builtin_amdgcn_mfma_f32_16x16x32_f16(a[2], bf[2][1], Z, 0, 0, 0); \
        f32x4 p20 = __builtin_amdgcn_mfma_f32_16x16x32_f16(a[4], bf[4][0], Z, 0, 0, 0); \
        f32x4 p21 = __builtin_amdgcn_mfma_f32_16x16x32_f16(a[4], bf[4][1], Z, 0, 0, 0); \
        f32x4 p30 = __builtin_amdgcn_mfma_f32_16x16x32_f16(a[6], bf[6][0], Z, 0, 0, 0); \
        f32x4 p31 = __builtin_amdgcn_mfma_f32_16x16x32_f16(a[6], bf[6][1], Z, 0, 0, 0); \
        p00 = __builtin_amdgcn_mfma_f32_16x16x32_f16(a[1], bf[1][0], p00, 0, 0, 0); \
        p01 = __builtin_amdgcn_mfma_f32_16x16x32_f16(a[1], bf[1][1], p01, 0, 0, 0); \
        p10 = __builtin_amdgcn_mfma_f32_16x16x32_f16(a[3], bf[3][0], p10, 0, 0, 0); \
        p11 = __builtin_amdgcn_mfma_f32_16x16x32_f16(a[3], bf[3][1], p11, 0, 0, 0); \
        p20 = __builtin_amdgcn_mfma_f32_16x16x32_f16(a[5], bf[5][0], p20, 0, 0, 0); \
        p21 = __builtin_amdgcn_mfma_f32_16x16x32_f16(a[5], bf[5][1], p21, 0, 0, 0); \
        p30 = __builtin_amdgcn_mfma_f32_16x16x32_f16(a[7], bf[7][0], p30, 0, 0, 0); \
        p31 = __builtin_amdgcn_mfma_f32_16x16x32_f16(a[7], bf[7][1], p31, 0, 0, 0); \
        float v0 = fast_tanh(((p00[0] + p10[0]) + (p20[0] + p30[0])) + CV0);        \
        float v1 = fast_tanh(((p01[0] + p11[0]) + (p21[0] + p31[0])) + CV1);        \
        if (lane < 16) {                                                            \
            hbuf[NXT][i0] = (f16)v0;                                                \
            hbuf[NXT][i1] = (f16)v1;                                                \
            ho[i0] = v0;                                                            \
            ho[i1] = v1;                                                            \
        }                                                                           \
        ho += HID;                                                                  \
        asm volatile("s_waitcnt lgkmcnt(0)\n\ts_barrier" ::: "memory");             \
    }

        for (int ch = 0; ch < NCHK; ++ch) {
            if (tid == 0) {
                while (__hip_atomic_load(&flags[8 + b], __ATOMIC_ACQUIRE, __HIP_MEMORY_SCOPE_AGENT) < ch + 1)
                    __builtin_amdgcn_s_sleep(2);
            }
            __syncthreads();
            const float* cc = cq + (size_t)ch * CH * HID;
            float d00 = cc[0*HID+i0], d01 = cc[0*HID+i1];
            float d10 = cc[1*HID+i0], d11 = cc[1*HID+i1];
            float d20 = cc[2*HID+i0], d21 = cc[2*HID+i1];
            float d30 = cc[3*HID+i0], d31 = cc[3*HID+i1];
            float d40 = cc[4*HID+i0], d41 = cc[4*HID+i1];
            float d50 = cc[5*HID+i0], d51 = cc[5*HID+i1];
            float d60 = cc[6*HID+i0], d61 = cc[6*HID+i1];
            float d70 = cc[7*HID+i0], d71 = cc[7*HID+i1];
            CSTEP(0, 1, d00, d01) CSTEP(1, 0, d10, d11)
            CSTEP(0, 1, d20, d21) CSTEP(1, 0, d30, d31)
            CSTEP(0, 1, d40, d41) CSTEP(1, 0, d50, d51)
            CSTEP(0, 1, d60, d61) CSTEP(1, 0, d70, d71)
        }
#undef CSTEP
    }
}

// tq[b][t][i] = tanh(Hs@Wq^T), tkT[b][i][t] = tanh(Hs@Wk^T)
__global__ __launch_bounds__(256) void gemmqk_kernel(
    const float* __restrict__ In, const float* __restrict__ Wq,
    const float* __restrict__ Wk, float* __restrict__ Oq, float* __restrict__ OkT)
{
    int b  = blockIdx.x & 7;
    int t0 = (blockIdx.x >> 3) * 8;
    int tid = threadIdx.x;
    __shared__ float hs[8][HID];
    for (int idx = tid; idx < 8 * HID; idx += 256) {
        int tt = idx >> 8, j = idx & 255;
        hs[tt][j] = In[((size_t)b * TT + t0 + tt) * HID + j];
    }
    __syncthreads();
    int i = tid;
    float aq[8], ak[8];
#pragma unroll
    for (int tt = 0; tt < 8; ++tt) { aq[tt] = 0.f; ak[tt] = 0.f; }
    const float* wq = Wq + i * HID;
    const float* wk = Wk + i * HID;
    for (int j = 0; j < HID; j += 4) {
        float4 q = *(const float4*)&wq[j];
        float4 k = *(const float4*)&wk[j];
#pragma unroll
        for (int tt = 0; tt < 8; ++tt) {
            float4 h = *(const float4*)&hs[tt][j];
            aq[tt] += h.x * q.x + h.y * q.y + h.z * q.z + h.w * q.w;
            ak[tt] += h.x * k.x + h.y * k.y + h.z * k.z + h.w * k.w;
        }
    }
#pragma unroll
    for (int tt = 0; tt < 8; ++tt)
        Oq[((size_t)b * TT + t0 + tt) * HID + i] = fast_tanh(aq[tt]);
    float4 kv0 = { fast_tanh(ak[0]), fast_tanh(ak[1]), fast_tanh(ak[2]), fast_tanh(ak[3]) };
    float4 kv1 = { fast_tanh(ak[4]), fast_tanh(ak[5]), fast_tanh(ak[6]), fast_tanh(ak[7]) };
    float* ko = OkT + ((size_t)b * HID + i) * TT + t0;
    *(float4*)&ko[0] = kv0;
    *(float4*)&ko[4] = kv1;
}

// attn (R8-verified): tanh addition identity; batch pinned to XCD; padded cvec.
__global__ __launch_bounds__(256) void attn_kernel(
    const float* __restrict__ tq, const float* __restrict__ tkT,
    const float* __restrict__ vvec, const float* __restrict__ Hs,
    const float* __restrict__ Wfc, const float* __restrict__ bfc,
    float* __restrict__ out)
{
    int b  = blockIdx.x & 7;
    int t0 = (blockIdx.x >> 3) * TG;
    int tid = threadIdx.x;
    int wave = tid >> 6, lane = tid & 63;
    __shared__ float qs[TG][HID], vs[HID], alpha[TG][HID];
    __shared__ float cvec[TG][8][68];
    __shared__ float redm[4][TG], reds[4][TG];
#pragma unroll
    for (int j = 0; j < TG; ++j)
        qs[j][tid] = tq[((size_t)b * TT + t0 + j) * HID + tid];
    vs[tid] = vvec[tid];
    __syncthreads();

    float sc[TG];
#pragma unroll
    for (int j = 0; j < TG; ++j) sc[j] = -1e30f;
    if ((wave << 6) < t0 + TG) {
        const float* kT = tkT + (size_t)b * HID * TT + tid;
        float a0 = 0.f, a1 = 0.f, a2 = 0.f, a3 = 0.f;
        for (int jj = 0; jj < HID; jj += 4) {
            float k0 = kT[(size_t)(jj + 0) * TT];
            float k1 = kT[(size_t)(jj + 1) * TT];
            float k2 = kT[(size_t)(jj + 2) * TT];
            float k3 = kT[(size_t)(jj + 3) * TT];
            float4 vv = *(const float4*)&vs[jj];
            float4 q0 = *(const float4*)&qs[0][jj];
            float4 q1 = *(const float4*)&qs[1][jj];
            float4 q2 = *(const float4*)&qs[2][jj];
            float4 q3 = *(const float4*)&qs[3][jj];
#define TADD(qc, kc, vc, acc) { float num = qc + kc; float den = __builtin_fmaf(qc, kc, 1.f); acc += vc * num * __builtin_amdgcn_rcpf(den); }
            TADD(q0.x, k0, vv.x, a0) TADD(q0.y, k1, vv.y, a0) TADD(q0.z, k2, vv.z, a0) TADD(q0.w, k3, vv.w, a0)
            TADD(q1.x, k0, vv.x, a1) TADD(q1.y, k1, vv.y, a1) TADD(q1.z, k2, vv.z, a1) TADD(q1.w, k3, vv.w, a1)
            TADD(q2.x, k0, vv.x, a2) TADD(q2.y, k1, vv.y, a2) TADD(q2.z, k2, vv.z, a2) TADD(q2.w, k3, vv.w, a2)
            TADD(q3.x, k0, vv.x, a3) TADD(q3.y, k1, vv.y, a3) TADD(q3.z, k2, vv.z, a3) TADD(q3.w, k3, vv.w, a3)
#undef TADD
        }
        if (tid < t0 + 0) sc[0] = a0;
        if (tid < t0 + 1) sc[1] = a1;
        if (tid < t0 + 2) sc[2] = a2;
        if (tid < t0 + 3) sc[3] = a3;
    }
    float m0 = sc[0], m1 = sc[1], m2 = sc[2], m3 = sc[3];
#pragma unroll
    for (int off = 32; off; off >>= 1) {
        m0 = fmaxf(m0, __shfl_down(m0, off));
        m1 = fmaxf(m1, __shfl_down(m1, off));
        m2 = fmaxf(m2, __shfl_down(m2, off));
        m3 = fmaxf(m3, __shfl_down(m3, off));
    }
    if (lane == 0) { redm[wave][0] = m0; redm[wave][1] = m1; redm[wave][2] = m2; redm[wave][3] = m3; }
    __syncthreads();
    float ej[TG];
#pragma unroll
    for (int j = 0; j < TG; ++j) {
        float m = fmaxf(fmaxf(redm[0][j], redm[1][j]), fmaxf(redm[2][j], redm[3][j]));
        ej[j] = (tid < t0 + j) ? exp2f((sc[j] - m) * 1.4426950408889634f) : 0.f;
    }
    float z0 = ej[0], z1 = ej[1], z2 = ej[2], z3 = ej[3];
#pragma unroll
    for (int off = 32; off; off >>= 1) {
        z0 += __shfl_down(z0, off);
        z1 += __shfl_down(z1, off);
        z2 += __shfl_down(z2, off);
        z3 += __shfl_down(z3, off);
    }
    if (lane == 0) { reds[wave][0] = z0; reds[wave][1] = z1; reds[wave][2] = z2; reds[wave][3] = z3; }
    __syncthreads();
#pragma unroll
    for (int j = 0; j < TG; ++j) {
        float z = reds[0][j] + reds[1][j] + reds[2][j] + reds[3][j];
        alpha[j][tid] = (t0 + j == 0) ? 0.f : ej[j] * __builtin_amdgcn_rcpf(z);
    }
    __syncthreads();

    float c0 = 0.f, c1 = 0.f, c2 = 0.f, c3 = 0.f;
    const float* hb = Hs + (size_t)b * TT * HID;
    for (int s = 0; s < t0 + TG; s += 4) {
        float4 av0 = *(const float4*)&alpha[0][s];
        float4 av1 = *(const float4*)&alpha[1][s];
        float4 av2 = *(const float4*)&alpha[2][s];
        float4 av3 = *(const float4*)&alpha[3][s];
        float h0 = hb[(s + 0) * HID + tid];
        float h1 = hb[(s + 1) * HID + tid];
        float h2 = hb[(s + 2) * HID + tid];
        float h3 = hb[(s + 3) * HID + tid];
        c0 += av0.x * h0 + av0.y * h1 + av0.z * h2 + av0.w * h3;
        c1 += av1.x * h0 + av1.y * h1 + av1.z * h2 + av1.w * h3;
        c2 += av2.x * h0 + av2.y * h1 + av2.z * h2 + av2.w * h3;
        c3 += av3.x * h0 + av3.y * h1 + av3.z * h2 + av3.w * h3;
    }
    {
        int ph = tid >> 6, jj = tid & 63;
        cvec[0][ph][jj] = hb[(size_t)(t0 + 0) * HID + tid]; cvec[0][4 + ph][jj] = c0;
        cvec[1][ph][jj] = hb[(size_t)(t0 + 1) * HID + tid]; cvec[1][4 + ph][jj] = c1;
        cvec[2][ph][jj] = hb[(size_t)(t0 + 2) * HID + tid]; cvec[2][4 + ph][jj] = c2;
        cvec[3][ph][jj] = hb[(size_t)(t0 + 3) * HID + tid]; cvec[3][4 + ph][jj] = c3;
    }
    __syncthreads();

    if (tid < VOCAB * 8) {
        int o = tid >> 3, p = tid & 7;
        const float* wr = Wfc + o * 2 * HID + p * 64;
#pragma unroll
        for (int j = 0; j < TG; ++j) {
            const float* cv = &cvec[j][p][0];
            float a = 0.f;
            for (int jj = 0; jj < 64; jj += 4) {
                float4 w  = *(const float4*)&wr[jj];
                float4 cc = *(const float4*)&cv[jj];
                a += w.x * cc.x + w.y * cc.y + w.z * cc.z + w.w * cc.w;
            }
            a += __shfl_down(a, 4);
            a += __shfl_down(a, 2);
            a += __shfl_down(a, 1);
            if (p == 0) out[((size_t)b * TT + t0 + j) * VOCAB + o] = a + bfc[o];
        }
    }
}

extern "C" void kernel_launch(void* const* d_in, const int* in_sizes, int n_in,
                              void* d_out, int out_size, void* d_ws, size_t ws_size,
                              hipStream_t stream)
{
    (void)in_sizes; (void)n_in; (void)out_size; (void)ws_size;
    const int*   x     = (const int*)d_in[0];
    const float* embed = (const float*)d_in[1];
    const float* Wih0  = (const float*)d_in[2];
    const float* bih0  = (const float*)d_in[3];
    const float* Whh0  = (const float*)d_in[4];
    const float* bhh0  = (const float*)d_in[5];
    const float* Wih1  = (const float*)d_in[6];
    const float* bih1  = (const float*)d_in[7];
    const float* Whh1  = (const float*)d_in[8];
    const float* bhh1  = (const float*)d_in[9];
    const float* Wq    = (const float*)d_in[10];
    const float* Wk    = (const float*)d_in[11];
    const float* vvec  = (const float*)d_in[12];
    const float* Wfc   = (const float*)d_in[13];
    const float* bfc   = (const float*)d_in[14];
    float* out = (float*)d_out;
    float* ws  = (float*)d_ws;

    const size_t SZ = (size_t)TT * BATCH * HID;  // 524288 floats = 2 MB
    float* C0   = ws;                    // reused as tq after rec3
    float* Hs   = ws + SZ;
    float* C1   = ws + 2 * SZ;           // reused as tkT after rec3
    f16*   H0h  = (f16*)(ws + 3 * SZ);   // SZ f16 = 1 MB
    int*   flags = (int*)(ws + 3 * SZ + SZ / 2);
    float* tq   = ws;
    float* tkT  = ws + 2 * SZ;

    pre0_kernel<<<256, 256, 0, stream>>>(x, embed, Wih0, bih0, bhh0, C0, flags);
    rec3_kernel<<<24, 512, 0, stream>>>(Whh0, Wih1, Whh1, bih1, bhh1, C0, H0h, C1, Hs, flags);
    gemmqk_kernel<<<256, 256, 0, stream>>>(Hs, Wq, Wk, tq, tkT);
    attn_kernel<<<512, 256, 0, stream>>>(tq, tkT, vvec, Hs, Wfc, bfc, out);
}